// Round 1
// baseline (4048.104 us; speedup 1.0000x reference)
//
#include <hip/hip_runtime.h>
#include <hip/hip_bf16.h>
#include <math.h>

#define Dd   512
#define Hn   8
#define HDm  64
#define Bn   2
#define Ln   4096
#define NPn  2048
#define QT   16
#define KT   128
#define INV_T 1.42857142857142857f   // 1/0.7

// ---------------------------------------------------------------------------
// LayerNorm: one wave (64 threads) per row of 512. Rows [0, B*L) come from x,
// rows [B*L, B*L+NP) come from the query bank.
// ---------------------------------------------------------------------------
__global__ __launch_bounds__(64) void ln_kernel(
    const float* __restrict__ x, const float* __restrict__ qsrc,
    const float* __restrict__ gx, const float* __restrict__ bx,
    const float* __restrict__ gq, const float* __restrict__ bq,
    float* __restrict__ xn, float* __restrict__ qn)
{
    int row = blockIdx.x;
    const float* src; float* dst; const float* g; const float* be;
    if (row < Bn * Ln) {
        src = x + (size_t)row * Dd; dst = xn + (size_t)row * Dd; g = gx; be = bx;
    } else {
        int r = row - Bn * Ln;
        src = qsrc + (size_t)r * Dd; dst = qn + (size_t)r * Dd; g = gq; be = bq;
    }
    int t = threadIdx.x;
    float4 v0 = ((const float4*)src)[2 * t];
    float4 v1 = ((const float4*)src)[2 * t + 1];
    float s = v0.x + v0.y + v0.z + v0.w + v1.x + v1.y + v1.z + v1.w;
#pragma unroll
    for (int o = 32; o > 0; o >>= 1) s += __shfl_down(s, o);
    float mu = __shfl(s, 0) * (1.0f / Dd);
    float a0 = v0.x - mu, a1 = v0.y - mu, a2 = v0.z - mu, a3 = v0.w - mu;
    float a4 = v1.x - mu, a5 = v1.y - mu, a6 = v1.z - mu, a7 = v1.w - mu;
    float s2 = a0*a0 + a1*a1 + a2*a2 + a3*a3 + a4*a4 + a5*a5 + a6*a6 + a7*a7;
#pragma unroll
    for (int o = 32; o > 0; o >>= 1) s2 += __shfl_down(s2, o);
    float rstd = rsqrtf(__shfl(s2, 0) * (1.0f / Dd) + 1e-5f);
    float4 g0 = ((const float4*)g)[2 * t],  g1 = ((const float4*)g)[2 * t + 1];
    float4 b0 = ((const float4*)be)[2 * t], b1 = ((const float4*)be)[2 * t + 1];
    float4 o0, o1;
    o0.x = a0 * rstd * g0.x + b0.x; o0.y = a1 * rstd * g0.y + b0.y;
    o0.z = a2 * rstd * g0.z + b0.z; o0.w = a3 * rstd * g0.w + b0.w;
    o1.x = a4 * rstd * g1.x + b1.x; o1.y = a5 * rstd * g1.y + b1.y;
    o1.z = a6 * rstd * g1.z + b1.z; o1.w = a7 * rstd * g1.w + b1.w;
    ((float4*)dst)[2 * t] = o0;
    ((float4*)dst)[2 * t + 1] = o1;
}

// ---------------------------------------------------------------------------
// Projection GEMM: C[m][n] = scale * (sum_k A[m][k] * W[n][k] + bias[n])
// BM=BN=64, BK=16, 256 threads, 4x4 per thread.
// ---------------------------------------------------------------------------
__global__ __launch_bounds__(256) void proj_kernel(
    const float* __restrict__ A, const float* __restrict__ W,
    const float* __restrict__ bias, float* __restrict__ C,
    int M, float scale)
{
    __shared__ float As[64][17];
    __shared__ float Ws[64][17];
    int bm = blockIdx.x * 64, bn = blockIdx.y * 64;
    int t = threadIdx.x;
    int tx = t & 15, ty = t >> 4;
    float acc[4][4] = {};
    for (int k0 = 0; k0 < Dd; k0 += 16) {
        int lr = t >> 2, lc = (t & 3) << 2;
        float4 av = *(const float4*)&A[(size_t)(bm + lr) * Dd + k0 + lc];
        As[lr][lc] = av.x; As[lr][lc + 1] = av.y; As[lr][lc + 2] = av.z; As[lr][lc + 3] = av.w;
        float4 wv = *(const float4*)&W[(size_t)(bn + lr) * Dd + k0 + lc];
        Ws[lr][lc] = wv.x; Ws[lr][lc + 1] = wv.y; Ws[lr][lc + 2] = wv.z; Ws[lr][lc + 3] = wv.w;
        __syncthreads();
#pragma unroll
        for (int k = 0; k < 16; ++k) {
            float a[4], b[4];
#pragma unroll
            for (int i = 0; i < 4; ++i) a[i] = As[ty * 4 + i][k];
#pragma unroll
            for (int j = 0; j < 4; ++j) b[j] = Ws[tx * 4 + j][k];
#pragma unroll
            for (int i = 0; i < 4; ++i)
#pragma unroll
                for (int j = 0; j < 4; ++j) acc[i][j] += a[i] * b[j];
        }
        __syncthreads();
    }
    float4 bv = *(const float4*)&bias[bn + tx * 4];
    float bb[4] = {bv.x, bv.y, bv.z, bv.w};
#pragma unroll
    for (int i = 0; i < 4; ++i) {
        int m = bm + ty * 4 + i;
        float4 ov;
        ov.x = scale * (acc[i][0] + bb[0]);
        ov.y = scale * (acc[i][1] + bb[1]);
        ov.z = scale * (acc[i][2] + bb[2]);
        ov.w = scale * (acc[i][3] + bb[3]);
        *(float4*)&C[(size_t)m * Dd + bn + tx * 4] = ov;
    }
}

// ---------------------------------------------------------------------------
// Attention kernel. One block = (batch b, 16-query tile). 256 threads, 4 waves.
// Wave wv owns queries q0+wv*4 .. +3; lane ln handles key columns {ln, ln+64}
// of each 128-key tile in the score phases, and d = ln*8..ln*8+7 in the
// output phase.
// Pass 1: per (q,h) online max m and sumexp Z over all L.
// Pass 2: recompute scores, p = mean_h softmax_h, w = p^(1/T) (temperature
// re-softmax, unnormalized), accumulate out' = sum_l w * xn[l], r = sum_l w;
// final out = out'/r.
// ---------------------------------------------------------------------------
__device__ __forceinline__ void score8(
    const float (*qp_s)[Dd], const float (*kx)[68],
    int wv, int ln, int h, float s[4][2])
{
    int l0 = ln, l1 = ln + 64;
#pragma unroll
    for (int d4 = 0; d4 < HDm; d4 += 4) {
        float4 k0 = *(const float4*)&kx[l0][d4];
        float4 k1 = *(const float4*)&kx[l1][d4];
#pragma unroll
        for (int i = 0; i < 4; ++i) {
            float4 qv = *(const float4*)&qp_s[wv * 4 + i][h * HDm + d4];
            s[i][0] += qv.x * k0.x + qv.y * k0.y + qv.z * k0.z + qv.w * k0.w;
            s[i][1] += qv.x * k1.x + qv.y * k1.y + qv.z * k1.z + qv.w * k1.w;
        }
    }
}

__global__ __launch_bounds__(256, 2) void attn_kernel(
    const float* __restrict__ qp,   // [NP][512] (scaled by 1/8)
    const float* __restrict__ kp,   // [B][L][512]
    const float* __restrict__ xn,   // [B][L][512]
    float* __restrict__ out)        // [B][NP][512]
{
    __shared__ __align__(16) float qp_s[QT][Dd];     // 32 KB
    __shared__ __align__(16) float kx_s[KT][68];     // 34 KB (also reused as xn tile)
    __shared__ __align__(16) float p_s[QT][KT];      // 8 KB
    __shared__ float m_s[QT][Hn];
    __shared__ float iz_s[QT][Hn];

    float (*xn_s)[Dd] = reinterpret_cast<float (*)[Dd]>(kx_s);  // 16x512 <= 128*68

    int b  = blockIdx.y;
    int q0 = blockIdx.x * QT;
    int t  = threadIdx.x;
    int wv = t >> 6;
    int ln = t & 63;

    const float* kpb = kp + (size_t)b * Ln * Dd;
    const float* xnb = xn + (size_t)b * Ln * Dd;

    // stage qp tile (16 x 512)
    for (int i = 0; i < 8; ++i) {
        int idx = i * 256 + t;
        int r = idx >> 7, c = idx & 127;
        ((float4*)&qp_s[r][0])[c] = ((const float4*)&qp[(size_t)(q0 + r) * Dd])[c];
    }

    // ------------------- Pass 1: per-(q,h) stats -------------------
    for (int h = 0; h < Hn; ++h) {
        float m[4], z[4];
#pragma unroll
        for (int i = 0; i < 4; ++i) { m[i] = -1e30f; z[i] = 0.f; }
        for (int t0 = 0; t0 < Ln; t0 += KT) {
            __syncthreads();
            for (int i = 0; i < 8; ++i) {
                int idx = i * 256 + t;
                int l = idx >> 4, d4 = (idx & 15) << 2;
                *(float4*)&kx_s[l][d4] =
                    *(const float4*)&kpb[(size_t)(t0 + l) * Dd + h * HDm + d4];
            }
            __syncthreads();
            float s[4][2] = {};
            score8(qp_s, kx_s, wv, ln, h, s);
#pragma unroll
            for (int i = 0; i < 4; ++i) {
                float tm = fmaxf(s[i][0], s[i][1]);
#pragma unroll
                for (int o = 32; o > 0; o >>= 1) tm = fmaxf(tm, __shfl_xor(tm, o));
                float mn = fmaxf(m[i], tm);
                float e = __expf(s[i][0] - mn) + __expf(s[i][1] - mn);
#pragma unroll
                for (int o = 32; o > 0; o >>= 1) e += __shfl_xor(e, o);
                z[i] = z[i] * __expf(m[i] - mn) + e;
                m[i] = mn;
            }
        }
        if (ln == 0) {
#pragma unroll
            for (int i = 0; i < 4; ++i) {
                m_s[wv * 4 + i][h]  = m[i];
                iz_s[wv * 4 + i][h] = 1.0f / (8.0f * z[i]);
            }
        }
    }

    // ------------------- Pass 2: p, temperature re-softmax, out -------------------
    float oacc[4][8] = {};
    float r[4] = {0.f, 0.f, 0.f, 0.f};

    for (int t0 = 0; t0 < Ln; t0 += KT) {
        float p[4][2] = {};
        for (int h = 0; h < Hn; ++h) {
            __syncthreads();
            for (int i = 0; i < 8; ++i) {
                int idx = i * 256 + t;
                int l = idx >> 4, d4 = (idx & 15) << 2;
                *(float4*)&kx_s[l][d4] =
                    *(const float4*)&kpb[(size_t)(t0 + l) * Dd + h * HDm + d4];
            }
            __syncthreads();
            float s[4][2] = {};
            score8(qp_s, kx_s, wv, ln, h, s);
#pragma unroll
            for (int i = 0; i < 4; ++i) {
                float mm = m_s[wv * 4 + i][h];
                float zz = iz_s[wv * 4 + i][h];
                p[i][0] += __expf(s[i][0] - mm) * zz;
                p[i][1] += __expf(s[i][1] - mm) * zz;
            }
        }
#pragma unroll
        for (int i = 0; i < 4; ++i) {
            float w0 = __expf(INV_T * __logf(p[i][0]));
            float w1 = __expf(INV_T * __logf(p[i][1]));
            p_s[wv * 4 + i][ln]      = w0;
            p_s[wv * 4 + i][64 + ln] = w1;
            r[i] += w0 + w1;
        }
        __syncthreads();   // p_s visible; all waves done reading kx_s

        for (int sub = 0; sub < KT; sub += 16) {
            if (sub) __syncthreads();
            for (int i = 0; i < 8; ++i) {
                int idx = i * 256 + t;
                int rr = idx >> 7, c = idx & 127;
                ((float4*)&xn_s[rr][0])[c] =
                    ((const float4*)&xnb[(size_t)(t0 + sub + rr) * Dd])[c];
            }
            __syncthreads();
            for (int l4 = 0; l4 < 16; l4 += 4) {
                float wf[4][4];
#pragma unroll
                for (int i = 0; i < 4; ++i) {
                    float4 w4 = *(const float4*)&p_s[wv * 4 + i][sub + l4];
                    wf[i][0] = w4.x; wf[i][1] = w4.y; wf[i][2] = w4.z; wf[i][3] = w4.w;
                }
#pragma unroll
                for (int j = 0; j < 4; ++j) {
                    float4 x0 = *(const float4*)&xn_s[l4 + j][ln * 8];
                    float4 x1 = *(const float4*)&xn_s[l4 + j][ln * 8 + 4];
#pragma unroll
                    for (int i = 0; i < 4; ++i) {
                        oacc[i][0] += wf[i][j] * x0.x;
                        oacc[i][1] += wf[i][j] * x0.y;
                        oacc[i][2] += wf[i][j] * x0.z;
                        oacc[i][3] += wf[i][j] * x0.w;
                        oacc[i][4] += wf[i][j] * x1.x;
                        oacc[i][5] += wf[i][j] * x1.y;
                        oacc[i][6] += wf[i][j] * x1.z;
                        oacc[i][7] += wf[i][j] * x1.w;
                    }
                }
            }
        }
    }

    // reduce r across the wave and write output
#pragma unroll
    for (int i = 0; i < 4; ++i) {
#pragma unroll
        for (int o = 32; o > 0; o >>= 1) r[i] += __shfl_xor(r[i], o);
    }
    float* ob = out + ((size_t)b * NPn + q0 + wv * 4) * Dd;
#pragma unroll
    for (int i = 0; i < 4; ++i) {
        float inv = 1.0f / r[i];
        float4 o0 = make_float4(oacc[i][0] * inv, oacc[i][1] * inv,
                                oacc[i][2] * inv, oacc[i][3] * inv);
        float4 o1 = make_float4(oacc[i][4] * inv, oacc[i][5] * inv,
                                oacc[i][6] * inv, oacc[i][7] * inv);
        *(float4*)&ob[(size_t)i * Dd + ln * 8]     = o0;
        *(float4*)&ob[(size_t)i * Dd + ln * 8 + 4] = o1;
    }
}

// ---------------------------------------------------------------------------
extern "C" void kernel_launch(void* const* d_in, const int* in_sizes, int n_in,
                              void* d_out, int out_size, void* d_ws, size_t ws_size,
                              hipStream_t stream)
{
    (void)in_sizes; (void)n_in; (void)out_size; (void)ws_size;
    const float* x       = (const float*)d_in[0];
    const float* queries = (const float*)d_in[1];
    const float* wq      = (const float*)d_in[2];
    const float* wk      = (const float*)d_in[3];
    const float* bq      = (const float*)d_in[4];
    const float* bk      = (const float*)d_in[5];
    const float* gq      = (const float*)d_in[6];
    const float* betq    = (const float*)d_in[7];
    const float* gx      = (const float*)d_in[8];
    const float* betx    = (const float*)d_in[9];
    float* out = (float*)d_out;

    float* ws  = (float*)d_ws;
    float* xn  = ws;                              // B*L*D   = 4,194,304 f
    float* kpb = xn  + (size_t)Bn * Ln * Dd;      // B*L*D   = 4,194,304 f
    float* qn  = kpb + (size_t)Bn * Ln * Dd;      // NP*D    = 1,048,576 f
    float* qpb = qn  + (size_t)NPn * Dd;          // NP*D    = 1,048,576 f
    // total ws use: 40 MB

    ln_kernel<<<Bn * Ln + NPn, 64, 0, stream>>>(x, queries, gx, betx, gq, betq, xn, qn);
    proj_kernel<<<dim3((Bn * Ln) / 64, Dd / 64), 256, 0, stream>>>(xn, wk, bk, kpb, Bn * Ln, 1.0f);
    proj_kernel<<<dim3(NPn / 64, Dd / 64), 256, 0, stream>>>(qn, wq, bq, qpb, NPn, 0.125f);
    attn_kernel<<<dim3(NPn / QT, Bn), 256, 0, stream>>>(qpb, kpb, xn, out);
}

// Round 2
// 920.831 us; speedup vs baseline: 4.3961x; 4.3961x over previous
//
#include <hip/hip_runtime.h>
#include <hip/hip_bf16.h>
#include <math.h>

#define Dd   512
#define Hn   8
#define HDm  64
#define Bn   2
#define Ln   4096
#define NPn  2048
#define QT   16
#define INV_T 1.42857142857142857f   // 1/0.7

typedef __attribute__((ext_vector_type(8))) short short8;   // 8 bf16 = 4 VGPR
typedef __attribute__((ext_vector_type(4))) float f32x4;

__device__ __forceinline__ ushort bf16_rne(float x) {
    uint u = __builtin_bit_cast(uint, x);
    return (ushort)((u + 0x7fffu + ((u >> 16) & 1u)) >> 16);
}
__device__ __forceinline__ float bf16_tof(ushort h) {
    uint u = ((uint)h) << 16; return __builtin_bit_cast(float, u);
}

// ---------------------------------------------------------------------------
// LayerNorm: one wave per row of 512.
// ---------------------------------------------------------------------------
__global__ __launch_bounds__(64) void ln_kernel(
    const float* __restrict__ x, const float* __restrict__ qsrc,
    const float* __restrict__ gx, const float* __restrict__ bx,
    const float* __restrict__ gq, const float* __restrict__ bq,
    float* __restrict__ xn, float* __restrict__ qn)
{
    int row = blockIdx.x;
    const float* src; float* dst; const float* g; const float* be;
    if (row < Bn * Ln) {
        src = x + (size_t)row * Dd; dst = xn + (size_t)row * Dd; g = gx; be = bx;
    } else {
        int r = row - Bn * Ln;
        src = qsrc + (size_t)r * Dd; dst = qn + (size_t)r * Dd; g = gq; be = bq;
    }
    int t = threadIdx.x;
    float4 v0 = ((const float4*)src)[2 * t];
    float4 v1 = ((const float4*)src)[2 * t + 1];
    float s = v0.x + v0.y + v0.z + v0.w + v1.x + v1.y + v1.z + v1.w;
#pragma unroll
    for (int o = 32; o > 0; o >>= 1) s += __shfl_down(s, o);
    float mu = __shfl(s, 0) * (1.0f / Dd);
    float a0 = v0.x - mu, a1 = v0.y - mu, a2 = v0.z - mu, a3 = v0.w - mu;
    float a4 = v1.x - mu, a5 = v1.y - mu, a6 = v1.z - mu, a7 = v1.w - mu;
    float s2 = a0*a0 + a1*a1 + a2*a2 + a3*a3 + a4*a4 + a5*a5 + a6*a6 + a7*a7;
#pragma unroll
    for (int o = 32; o > 0; o >>= 1) s2 += __shfl_down(s2, o);
    float rstd = rsqrtf(__shfl(s2, 0) * (1.0f / Dd) + 1e-5f);
    float4 g0 = ((const float4*)g)[2 * t],  g1 = ((const float4*)g)[2 * t + 1];
    float4 b0 = ((const float4*)be)[2 * t], b1 = ((const float4*)be)[2 * t + 1];
    float4 o0, o1;
    o0.x = a0 * rstd * g0.x + b0.x; o0.y = a1 * rstd * g0.y + b0.y;
    o0.z = a2 * rstd * g0.z + b0.z; o0.w = a3 * rstd * g0.w + b0.w;
    o1.x = a4 * rstd * g1.x + b1.x; o1.y = a5 * rstd * g1.y + b1.y;
    o1.z = a6 * rstd * g1.z + b1.z; o1.w = a7 * rstd * g1.w + b1.w;
    ((float4*)dst)[2 * t] = o0;
    ((float4*)dst)[2 * t + 1] = o1;
}

// ---------------------------------------------------------------------------
// Projection GEMM + bf16 hi/lo split epilogue.
// C = scale*(A @ W^T + bias); Chi = bf16(C), Clo = bf16(C - Chi).
// ---------------------------------------------------------------------------
__global__ __launch_bounds__(256) void proj_split(
    const float* __restrict__ A, const float* __restrict__ W,
    const float* __restrict__ bias,
    ushort* __restrict__ Chi, ushort* __restrict__ Clo, float scale)
{
    __shared__ float As[64][17];
    __shared__ float Ws[64][17];
    int bm = blockIdx.x * 64, bn = blockIdx.y * 64;
    int t = threadIdx.x;
    int tx = t & 15, ty = t >> 4;
    float acc[4][4] = {};
    for (int k0 = 0; k0 < Dd; k0 += 16) {
        int lr = t >> 2, lc = (t & 3) << 2;
        float4 av = *(const float4*)&A[(size_t)(bm + lr) * Dd + k0 + lc];
        As[lr][lc] = av.x; As[lr][lc + 1] = av.y; As[lr][lc + 2] = av.z; As[lr][lc + 3] = av.w;
        float4 wv = *(const float4*)&W[(size_t)(bn + lr) * Dd + k0 + lc];
        Ws[lr][lc] = wv.x; Ws[lr][lc + 1] = wv.y; Ws[lr][lc + 2] = wv.z; Ws[lr][lc + 3] = wv.w;
        __syncthreads();
#pragma unroll
        for (int k = 0; k < 16; ++k) {
            float a[4], b[4];
#pragma unroll
            for (int i = 0; i < 4; ++i) a[i] = As[ty * 4 + i][k];
#pragma unroll
            for (int j = 0; j < 4; ++j) b[j] = Ws[tx * 4 + j][k];
#pragma unroll
            for (int i = 0; i < 4; ++i)
#pragma unroll
                for (int j = 0; j < 4; ++j) acc[i][j] += a[i] * b[j];
        }
        __syncthreads();
    }
    float4 bv = *(const float4*)&bias[bn + tx * 4];
    float bb[4] = {bv.x, bv.y, bv.z, bv.w};
#pragma unroll
    for (int i = 0; i < 4; ++i) {
        int m = bm + ty * 4 + i;
        ushort hv[4], lv[4];
#pragma unroll
        for (int j = 0; j < 4; ++j) {
            float v = scale * (acc[i][j] + bb[j]);
            hv[j] = bf16_rne(v);
            lv[j] = bf16_rne(v - bf16_tof(hv[j]));
        }
        *(ushort4*)&Chi[(size_t)m * Dd + bn + tx * 4] = make_ushort4(hv[0], hv[1], hv[2], hv[3]);
        *(ushort4*)&Clo[(size_t)m * Dd + bn + tx * 4] = make_ushort4(lv[0], lv[1], lv[2], lv[3]);
    }
}

// ---------------------------------------------------------------------------
// Transpose + split: xn [B][L][D] f32  ->  xth/xtl [B][D][L] bf16.
// ---------------------------------------------------------------------------
__global__ __launch_bounds__(256) void transpose_split(
    const float* __restrict__ xn, ushort* __restrict__ xth, ushort* __restrict__ xtl)
{
    __shared__ float tile[64][65];
    int l0 = blockIdx.x * 64, d0 = blockIdx.y * 64, b = blockIdx.z;
    int t = threadIdx.x;
#pragma unroll
    for (int i = 0; i < 16; ++i) {
        int idx = i * 256 + t, lr = idx >> 6, lc = idx & 63;
        tile[lr][lc] = xn[((size_t)(b * Ln + l0 + lr)) * Dd + d0 + lc];
    }
    __syncthreads();
#pragma unroll
    for (int i = 0; i < 16; ++i) {
        int idx = i * 256 + t, dr = idx >> 6, lc = idx & 63;
        float v = tile[lc][dr];
        ushort hi = bf16_rne(v);
        ushort lo = bf16_rne(v - bf16_tof(hi));
        size_t o = ((size_t)(b * Dd + d0 + dr)) * Ln + l0 + lc;
        xth[o] = hi; xtl[o] = lo;
    }
}

// 6-MFMA split score tile: S += Qhi*Khi + Qhi*Klo + Qlo*Khi  (both k-halves).
// IDENTICAL sequence in pass1 and pass2 => bitwise-identical s.
#define SCORE6(acc, qhs, qls, kR, lR, lq, lg, h)                                   \
    {                                                                              \
        short8 ah0 = qhs[(lq * 64 + (h) * 8 + lg) ^ (lq & 7)];                     \
        short8 ah1 = qhs[(lq * 64 + (h) * 8 + 4 + lg) ^ (lq & 7)];                 \
        short8 al0 = qls[(lq * 64 + (h) * 8 + lg) ^ (lq & 7)];                     \
        short8 al1 = qls[(lq * 64 + (h) * 8 + 4 + lg) ^ (lq & 7)];                 \
        short8 bh0 = *(const short8*)&kR[(h) * 64];                                \
        short8 bh1 = *(const short8*)&kR[(h) * 64 + 32];                           \
        short8 bl0 = *(const short8*)&lR[(h) * 64];                                \
        short8 bl1 = *(const short8*)&lR[(h) * 64 + 32];                           \
        acc = __builtin_amdgcn_mfma_f32_16x16x32_bf16(ah0, bh0, acc, 0, 0, 0);     \
        acc = __builtin_amdgcn_mfma_f32_16x16x32_bf16(ah0, bl0, acc, 0, 0, 0);     \
        acc = __builtin_amdgcn_mfma_f32_16x16x32_bf16(al0, bh0, acc, 0, 0, 0);     \
        acc = __builtin_amdgcn_mfma_f32_16x16x32_bf16(ah1, bh1, acc, 0, 0, 0);     \
        acc = __builtin_amdgcn_mfma_f32_16x16x32_bf16(ah1, bl1, acc, 0, 0, 0);     \
        acc = __builtin_amdgcn_mfma_f32_16x16x32_bf16(al1, bh1, acc, 0, 0, 0);     \
    }

// ---------------------------------------------------------------------------
// Pass 1: Z[b][q][h] = sum_l exp(s).  No max tracking: |s| <= 64 worst case,
// exp(64)=6e27 and Z <= 4096*exp(64) < f32 max. Grid (128, 2, 4): each block
// covers a 1024-key chunk; 4 waves x 16 l-tiles each.
// ---------------------------------------------------------------------------
__global__ __launch_bounds__(256) void attn_pass1(
    const ushort* __restrict__ qh_g, const ushort* __restrict__ ql_g,
    const ushort* __restrict__ kh_g, const ushort* __restrict__ kl_g,
    float* __restrict__ zp)
{
    __shared__ __align__(16) short8 qhs[1024];
    __shared__ __align__(16) short8 qls[1024];
    __shared__ float zs[4][8][16];
    int q16 = blockIdx.x, b = blockIdx.y, ck = blockIdx.z;
    int t = threadIdx.x, wv = t >> 6, ln = t & 63;
    int q0 = q16 * QT;
    const short8* qh8 = (const short8*)qh_g;
    const short8* ql8 = (const short8*)ql_g;
#pragma unroll
    for (int it = 0; it < 4; ++it) {
        int idx = it * 256 + t; int r = idx >> 6;
        int slot = idx ^ (r & 7);                 // XOR-swizzle (T2)
        qhs[slot] = qh8[(size_t)(q0 + r) * 64 + (idx & 63)];
        qls[slot] = ql8[(size_t)(q0 + r) * 64 + (idx & 63)];
    }
    __syncthreads();
    int lq = ln & 15, lg = ln >> 4;
    float z[8][4] = {};
    size_t kbase = ((size_t)(b * Ln + ck * 1024 + wv * 16 + lq)) * Dd + lg * 8;
    for (int step = 0; step < 16; ++step) {
        const short* kR = (const short*)kh_g + kbase + (size_t)step * 64 * Dd;
        const short* lR = (const short*)kl_g + kbase + (size_t)step * 64 * Dd;
#pragma unroll
        for (int h = 0; h < 8; ++h) {
            f32x4 acc = {};
            SCORE6(acc, qhs, qls, kR, lR, lq, lg, h);
#pragma unroll
            for (int r = 0; r < 4; ++r) z[h][r] += __expf(acc[r]);
        }
    }
#pragma unroll
    for (int h = 0; h < 8; ++h)
#pragma unroll
        for (int r = 0; r < 4; ++r) {
            float v = z[h][r];
            v += __shfl_xor(v, 1); v += __shfl_xor(v, 2);
            v += __shfl_xor(v, 4); v += __shfl_xor(v, 8);
            z[h][r] = v;
        }
    if ((ln & 15) == 0) {
#pragma unroll
        for (int h = 0; h < 8; ++h)
#pragma unroll
            for (int r = 0; r < 4; ++r) zs[wv][h][lg * 4 + r] = z[h][r];
    }
    __syncthreads();
    if (t < 128) {
        int q = t >> 3, h = t & 7;
        float s = zs[0][h][q] + zs[1][h][q] + zs[2][h][q] + zs[3][h][q];
        zp[((((size_t)b * 128 + q16) * 4 + ck) * 16 + q) * 8 + h] = s;
    }
}

__global__ __launch_bounds__(256) void zreduce(
    const float* __restrict__ zp, float* __restrict__ izs)
{
    int g = blockIdx.x * 256 + threadIdx.x;           // 32768 total
    int b = g >> 14, rem = g & 16383;
    int q16 = rem >> 7, r2 = rem & 127, q = r2 >> 3, h = r2 & 7;
    float s = 0.f;
#pragma unroll
    for (int c = 0; c < 4; ++c)
        s += zp[((((size_t)b * 128 + q16) * 4 + c) * 16 + q) * 8 + h];
    izs[g] = 1.0f / (8.0f * s);                       // folds head-mean /8
}

// ---------------------------------------------------------------------------
// Pass 2: 512 threads (8 waves). Wave w scores l-tile t0+w*16 (all heads),
// p = sum_h exp(s)*izs; w = p^(1/T) -> bf16 -> shared P [16][128];
// PV: wave w computes out cols [w*64, w*64+64) over the whole 128-key step
// using split V^T.  Out written directly (no partials).
// ---------------------------------------------------------------------------
__global__ __launch_bounds__(512) void attn_pass2(
    const ushort* __restrict__ qh_g, const ushort* __restrict__ ql_g,
    const ushort* __restrict__ kh_g, const ushort* __restrict__ kl_g,
    const ushort* __restrict__ vh_g, const ushort* __restrict__ vl_g,
    const float* __restrict__ izs, float* __restrict__ out)
{
    __shared__ __align__(16) short8 qhs[1024];
    __shared__ __align__(16) short8 qls[1024];
    __shared__ __align__(16) ushort Ps[QT * 128];
    __shared__ float izss[QT * 8];
    __shared__ float rss[8][16];
    int q16 = blockIdx.x, b = blockIdx.y;
    int t = threadIdx.x, wv = t >> 6, ln = t & 63;
    int q0 = q16 * QT;
    const short8* qh8 = (const short8*)qh_g;
    const short8* ql8 = (const short8*)ql_g;
#pragma unroll
    for (int it = 0; it < 2; ++it) {
        int idx = it * 512 + t; int r = idx >> 6;
        int slot = idx ^ (r & 7);
        qhs[slot] = qh8[(size_t)(q0 + r) * 64 + (idx & 63)];
        qls[slot] = ql8[(size_t)(q0 + r) * 64 + (idx & 63)];
    }
    if (t < 128) izss[t] = izs[((size_t)b * NPn + q0 + (t >> 3)) * 8 + (t & 7)];
    __syncthreads();

    int lq = ln & 15, lg = ln >> 4;
    f32x4 oacc[4] = {};
    float racc[4] = {0.f, 0.f, 0.f, 0.f};
    const short8* Ps8 = (const short8*)Ps;

    for (int t0 = 0; t0 < Ln; t0 += 128) {
        size_t krow = ((size_t)(b * Ln + t0 + wv * 16 + lq)) * Dd + lg * 8;
        const short* kR = (const short*)kh_g + krow;
        const short* lR = (const short*)kl_g + krow;
        float p[4] = {0.f, 0.f, 0.f, 0.f};
#pragma unroll
        for (int h = 0; h < 8; ++h) {
            f32x4 acc = {};
            SCORE6(acc, qhs, qls, kR, lR, lq, lg, h);
#pragma unroll
            for (int r = 0; r < 4; ++r)
                p[r] += __expf(acc[r]) * izss[(lg * 4 + r) * 8 + h];
        }
#pragma unroll
        for (int r = 0; r < 4; ++r) {
            float wgt = __expf(INV_T * __logf(p[r]));   // p^(1/T)
            ushort uw = bf16_rne(wgt);
            racc[r] += bf16_tof(uw);                    // denominator uses same rounded w
            int q = lg * 4 + r;
            int e = q * 128 + wv * 16 + lq;
            Ps[e ^ ((q & 7) << 3)] = uw;
        }
        __syncthreads();
        // ---- PV: O += P * V^T ----
        short8 pa[4];
#pragma unroll
        for (int ks = 0; ks < 4; ++ks)
            pa[ks] = Ps8[(lq * 16 + ks * 4 + lg) ^ (lq & 7)];
#pragma unroll
        for (int n = 0; n < 4; ++n) {
            int d = wv * 64 + n * 16 + lq;
            size_t vrow = ((size_t)(b * Dd + d)) * Ln + t0 + lg * 8;
            const short* vR = (const short*)vh_g + vrow;
            const short* wR = (const short*)vl_g + vrow;
#pragma unroll
            for (int ks = 0; ks < 4; ++ks) {
                short8 bh = *(const short8*)&vR[ks * 32];
                short8 bl = *(const short8*)&wR[ks * 32];
                oacc[n] = __builtin_amdgcn_mfma_f32_16x16x32_bf16(pa[ks], bh, oacc[n], 0, 0, 0);
                oacc[n] = __builtin_amdgcn_mfma_f32_16x16x32_bf16(pa[ks], bl, oacc[n], 0, 0, 0);
            }
        }
        __syncthreads();   // P_s reused next iteration
    }

#pragma unroll
    for (int r = 0; r < 4; ++r) {
        float v = racc[r];
        v += __shfl_xor(v, 1); v += __shfl_xor(v, 2);
        v += __shfl_xor(v, 4); v += __shfl_xor(v, 8);
        racc[r] = v;
    }
    if ((ln & 15) == 0) {
#pragma unroll
        for (int r = 0; r < 4; ++r) rss[wv][lg * 4 + r] = racc[r];
    }
    __syncthreads();
#pragma unroll
    for (int r = 0; r < 4; ++r) {
        int q = lg * 4 + r;
        float rt = 0.f;
#pragma unroll
        for (int w2 = 0; w2 < 8; ++w2) rt += rss[w2][q];
        float inv = 1.0f / rt;
#pragma unroll
        for (int n = 0; n < 4; ++n)
            out[((size_t)(b * NPn + q0 + q)) * Dd + wv * 64 + n * 16 + lq] = oacc[n][r] * inv;
    }
}

// ---------------------------------------------------------------------------
extern "C" void kernel_launch(void* const* d_in, const int* in_sizes, int n_in,
                              void* d_out, int out_size, void* d_ws, size_t ws_size,
                              hipStream_t stream)
{
    (void)in_sizes; (void)n_in; (void)out_size; (void)ws_size;
    const float* x       = (const float*)d_in[0];
    const float* queries = (const float*)d_in[1];
    const float* wq      = (const float*)d_in[2];
    const float* wk      = (const float*)d_in[3];
    const float* bq      = (const float*)d_in[4];
    const float* bk      = (const float*)d_in[5];
    const float* gq      = (const float*)d_in[6];
    const float* betq    = (const float*)d_in[7];
    const float* gx      = (const float*)d_in[8];
    const float* betx    = (const float*)d_in[9];

    float* ws  = (float*)d_ws;
    float*  xn  = ws;                                   //  4,194,304 f
    float*  qn  = xn + (size_t)Bn * Ln * Dd;            //  1,048,576 f
    ushort* kh  = (ushort*)(qn + (size_t)NPn * Dd);     //  4,194,304 u16
    ushort* kl  = kh + (size_t)Bn * Ln * Dd;
    ushort* qh  = kl + (size_t)Bn * Ln * Dd;            //  1,048,576 u16
    ushort* ql  = qh + (size_t)NPn * Dd;
    ushort* vh  = ql + (size_t)NPn * Dd;                //  4,194,304 u16
    ushort* vl  = vh + (size_t)Bn * Ln * Dd;
    float*  zp  = (float*)(vl + (size_t)Bn * Ln * Dd);  //    131,072 f
    float*  izs = zp + 131072;                          //     32,768 f
    // total ~59.4 MB

    ln_kernel<<<Bn * Ln + NPn, 64, 0, stream>>>(x, queries, gx, betx, gq, betq, xn, qn);
    proj_split<<<dim3((Bn * Ln) / 64, Dd / 64), 256, 0, stream>>>(xn, wk, bk, kh, kl, 1.0f);
    proj_split<<<dim3(NPn / 64, Dd / 64), 256, 0, stream>>>(qn, wq, bq, qh, ql, 0.125f);
    transpose_split<<<dim3(Ln / 64, Dd / 64, Bn), 256, 0, stream>>>(xn, vh, vl);
    attn_pass1<<<dim3(NPn / QT, Bn, 4), 256, 0, stream>>>(qh, ql, kh, kl, zp);
    zreduce<<<128, 256, 0, stream>>>(zp, izs);
    attn_pass2<<<dim3(NPn / QT, Bn), 512, 0, stream>>>(qh, ql, kh, kl, vh, vl, izs, (float*)d_out);
}

// Round 3
// 545.153 us; speedup vs baseline: 7.4256x; 1.6891x over previous
//
#include <hip/hip_runtime.h>
#include <hip/hip_bf16.h>
#include <math.h>

#define Dd   512
#define Hn   8
#define Bn   2
#define Ln   4096
#define NPn  2048
#define INV_T 1.42857142857142857f   // 1/0.7

typedef __attribute__((ext_vector_type(8))) short short8;   // 8 bf16 = 4 VGPR
typedef __attribute__((ext_vector_type(4))) float f32x4;

__device__ __forceinline__ ushort bf16_rne(float x) {
    uint u = __builtin_bit_cast(uint, x);
    return (ushort)((u + 0x7fffu + ((u >> 16) & 1u)) >> 16);
}
__device__ __forceinline__ float bf16_tof(ushort h) {
    uint u = ((uint)h) << 16; return __builtin_bit_cast(float, u);
}

// ---------------------------------------------------------------------------
// LayerNorm + hi/lo bf16 split. One wave per row of 512.
// Rows [0, B*L): x -> xh/xl.  Rows [B*L, B*L+NP): query bank -> qnh/qnl.
// ---------------------------------------------------------------------------
__global__ __launch_bounds__(64) void ln_split(
    const float* __restrict__ x, const float* __restrict__ qsrc,
    const float* __restrict__ gx, const float* __restrict__ bx,
    const float* __restrict__ gq, const float* __restrict__ bq,
    ushort* __restrict__ xh, ushort* __restrict__ xl,
    ushort* __restrict__ qnh, ushort* __restrict__ qnl)
{
    int row = blockIdx.x;
    const float* src; ushort* dh; ushort* dl; const float* g; const float* be;
    if (row < Bn * Ln) {
        src = x + (size_t)row * Dd; dh = xh + (size_t)row * Dd; dl = xl + (size_t)row * Dd;
        g = gx; be = bx;
    } else {
        int r = row - Bn * Ln;
        src = qsrc + (size_t)r * Dd; dh = qnh + (size_t)r * Dd; dl = qnl + (size_t)r * Dd;
        g = gq; be = bq;
    }
    int t = threadIdx.x;
    float4 v0 = ((const float4*)src)[2 * t];
    float4 v1 = ((const float4*)src)[2 * t + 1];
    float s = v0.x + v0.y + v0.z + v0.w + v1.x + v1.y + v1.z + v1.w;
#pragma unroll
    for (int o = 32; o > 0; o >>= 1) s += __shfl_down(s, o);
    float mu = __shfl(s, 0) * (1.0f / Dd);
    float a[8] = {v0.x - mu, v0.y - mu, v0.z - mu, v0.w - mu,
                  v1.x - mu, v1.y - mu, v1.z - mu, v1.w - mu};
    float s2 = 0.f;
#pragma unroll
    for (int i = 0; i < 8; ++i) s2 += a[i] * a[i];
#pragma unroll
    for (int o = 32; o > 0; o >>= 1) s2 += __shfl_down(s2, o);
    float rstd = rsqrtf(__shfl(s2, 0) * (1.0f / Dd) + 1e-5f);
    float4 g0 = ((const float4*)g)[2 * t],  g1 = ((const float4*)g)[2 * t + 1];
    float4 b0 = ((const float4*)be)[2 * t], b1 = ((const float4*)be)[2 * t + 1];
    float gv[8] = {g0.x, g0.y, g0.z, g0.w, g1.x, g1.y, g1.z, g1.w};
    float bv[8] = {b0.x, b0.y, b0.z, b0.w, b1.x, b1.y, b1.z, b1.w};
    ushort hv[8], lv[8];
#pragma unroll
    for (int i = 0; i < 8; ++i) {
        float v = a[i] * rstd * gv[i] + bv[i];
        hv[i] = bf16_rne(v);
        lv[i] = bf16_rne(v - bf16_tof(hv[i]));
    }
    *(ushort4*)&dh[t * 8]     = make_ushort4(hv[0], hv[1], hv[2], hv[3]);
    *(ushort4*)&dh[t * 8 + 4] = make_ushort4(hv[4], hv[5], hv[6], hv[7]);
    *(ushort4*)&dl[t * 8]     = make_ushort4(lv[0], lv[1], lv[2], lv[3]);
    *(ushort4*)&dl[t * 8 + 4] = make_ushort4(lv[4], lv[5], lv[6], lv[7]);
}

// ---------------------------------------------------------------------------
// Weight split: wq, wk (f32 512x512) -> hi/lo bf16.
// ---------------------------------------------------------------------------
__global__ __launch_bounds__(256) void wsplit(
    const float* __restrict__ wq, const float* __restrict__ wk,
    ushort* __restrict__ wqh, ushort* __restrict__ wql,
    ushort* __restrict__ wkh, ushort* __restrict__ wkl)
{
    int i = blockIdx.x * 256 + threadIdx.x;    // 0 .. 2*65536-1 (float4 units)
    const float* src; ushort* dh; ushort* dl;
    int j = i;
    if (i < 65536) { src = wq; dh = wqh; dl = wql; }
    else { j -= 65536; src = wk; dh = wkh; dl = wkl; }
    float4 v = ((const float4*)src)[j];
    float vv[4] = {v.x, v.y, v.z, v.w};
    ushort hv[4], lv[4];
#pragma unroll
    for (int k = 0; k < 4; ++k) {
        hv[k] = bf16_rne(vv[k]);
        lv[k] = bf16_rne(vv[k] - bf16_tof(hv[k]));
    }
    *(ushort4*)&dh[j * 4] = make_ushort4(hv[0], hv[1], hv[2], hv[3]);
    *(ushort4*)&dl[j * 4] = make_ushort4(lv[0], lv[1], lv[2], lv[3]);
}

// ---------------------------------------------------------------------------
// Projection GEMM, split-bf16 MFMA (3 products per K32):
// C = scale*(A @ W^T + bias), A and W given as hi/lo bf16 [.][512].
// Block: 64M x 256N, 4 waves; wave = 64M x 64N (qt=4, nf=4).
// Outputs hi/lo split of C.
// ---------------------------------------------------------------------------
__global__ __launch_bounds__(256, 2) void proj_mfma(
    const ushort* __restrict__ Ah, const ushort* __restrict__ Al,
    const ushort* __restrict__ Wh, const ushort* __restrict__ Wl,
    const float* __restrict__ bias,
    ushort* __restrict__ Chi, ushort* __restrict__ Clo, float scale)
{
    int bm = blockIdx.x * 64, bn = blockIdx.y * 256;
    int t = threadIdx.x, wv = t >> 6, ln = t & 63;
    int lq = ln & 15, lg = ln >> 4;
    f32x4 acc[4][4] = {};   // [qt][nf]
    for (int k0 = 0; k0 < Dd; k0 += 32) {
        short8 bh[4], bl[4];
#pragma unroll
        for (int nf = 0; nf < 4; ++nf) {
            size_t wr = (size_t)(bn + wv * 64 + nf * 16 + lq) * Dd + k0 + lg * 8;
            bh[nf] = *(const short8*)&Wh[wr];
            bl[nf] = *(const short8*)&Wl[wr];
        }
#pragma unroll
        for (int qt = 0; qt < 4; ++qt) {
            size_t ar = (size_t)(bm + qt * 16 + lq) * Dd + k0 + lg * 8;
            short8 ah = *(const short8*)&Ah[ar];
            short8 al = *(const short8*)&Al[ar];
#pragma unroll
            for (int nf = 0; nf < 4; ++nf) {
                acc[qt][nf] = __builtin_amdgcn_mfma_f32_16x16x32_bf16(ah, bh[nf], acc[qt][nf], 0, 0, 0);
                acc[qt][nf] = __builtin_amdgcn_mfma_f32_16x16x32_bf16(ah, bl[nf], acc[qt][nf], 0, 0, 0);
                acc[qt][nf] = __builtin_amdgcn_mfma_f32_16x16x32_bf16(al, bh[nf], acc[qt][nf], 0, 0, 0);
            }
        }
    }
    float bb[4];
#pragma unroll
    for (int nf = 0; nf < 4; ++nf) bb[nf] = bias[bn + wv * 64 + nf * 16 + lq];
#pragma unroll
    for (int qt = 0; qt < 4; ++qt)
#pragma unroll
        for (int nf = 0; nf < 4; ++nf)
#pragma unroll
            for (int r = 0; r < 4; ++r) {
                int m = bm + qt * 16 + lg * 4 + r;
                int n = bn + wv * 64 + nf * 16 + lq;
                float v = scale * (acc[qt][nf][r] + bb[nf]);
                ushort hi = bf16_rne(v);
                Chi[(size_t)m * Dd + n] = hi;
                Clo[(size_t)m * Dd + n] = bf16_rne(v - bf16_tof(hi));
            }
}

// ---------------------------------------------------------------------------
// Transpose hi/lo (packed as u32): [B][L][D] -> [B][D][L].
// ---------------------------------------------------------------------------
__global__ __launch_bounds__(256) void transpose_u16(
    const ushort* __restrict__ xh, const ushort* __restrict__ xl,
    ushort* __restrict__ vh, ushort* __restrict__ vl)
{
    __shared__ uint tile[64][65];
    int l0 = blockIdx.x * 64, d0 = blockIdx.y * 64, b = blockIdx.z;
    int t = threadIdx.x;
#pragma unroll
    for (int i = 0; i < 16; ++i) {
        int idx = i * 256 + t, lr = idx >> 6, lc = idx & 63;
        size_t o = ((size_t)(b * Ln + l0 + lr)) * Dd + d0 + lc;
        tile[lr][lc] = (uint)xh[o] | ((uint)xl[o] << 16);
    }
    __syncthreads();
#pragma unroll
    for (int i = 0; i < 16; ++i) {
        int idx = i * 256 + t, dr = idx >> 6, lc = idx & 63;
        uint v = tile[lc][dr];
        size_t o = ((size_t)(b * Dd + d0 + dr)) * Ln + l0 + lc;
        vh[o] = (ushort)(v & 0xffff);
        vl[o] = (ushort)(v >> 16);
    }
}

// 6-MFMA split score: S += Qhi*Khi + Qhi*Klo + Qlo*Khi (both k-halves).
#define MFMA6(acc, ah0, ah1, al0, al1, bh0, bh1, bl0, bl1)                         \
    acc = __builtin_amdgcn_mfma_f32_16x16x32_bf16(ah0, bh0, acc, 0, 0, 0);         \
    acc = __builtin_amdgcn_mfma_f32_16x16x32_bf16(ah0, bl0, acc, 0, 0, 0);         \
    acc = __builtin_amdgcn_mfma_f32_16x16x32_bf16(al0, bh0, acc, 0, 0, 0);         \
    acc = __builtin_amdgcn_mfma_f32_16x16x32_bf16(ah1, bh1, acc, 0, 0, 0);         \
    acc = __builtin_amdgcn_mfma_f32_16x16x32_bf16(ah1, bl1, acc, 0, 0, 0);         \
    acc = __builtin_amdgcn_mfma_f32_16x16x32_bf16(al1, bh1, acc, 0, 0, 0);

// ---------------------------------------------------------------------------
// Pass 1: zpart[ck*2+b][q][h] = sum over 512-key chunk of exp(s).
// Grid 1024 flat: combo = id&15 -> (b, ck 0..7), q16 = id>>4 (32 q each).
// 4 waves; wave handles 2 heads; Q frags in REGISTERS (no LDS, no barriers).
// ---------------------------------------------------------------------------
__global__ __launch_bounds__(256, 4) void attn_pass1(
    const ushort* __restrict__ qh_g, const ushort* __restrict__ ql_g,
    const ushort* __restrict__ kh_g, const ushort* __restrict__ kl_g,
    float* __restrict__ zpart)
{
    int orig = blockIdx.x;
    int combo = orig & 15, b = combo & 1, ck = combo >> 1;
    int q0 = (orig >> 4) * 32;
    int t = threadIdx.x, wv = t >> 6, ln = t & 63;
    int lq = ln & 15, lg = ln >> 4;
    int h0 = wv * 2;

    short8 AH[2][2][2], AL[2][2][2];   // [qt][hh][khalf]
#pragma unroll
    for (int qt = 0; qt < 2; ++qt)
#pragma unroll
        for (int hh = 0; hh < 2; ++hh)
#pragma unroll
            for (int hf = 0; hf < 2; ++hf) {
                size_t a = (size_t)(q0 + qt * 16 + lq) * Dd + (h0 + hh) * 64 + hf * 32 + lg * 8;
                AH[qt][hh][hf] = *(const short8*)&qh_g[a];
                AL[qt][hh][hf] = *(const short8*)&ql_g[a];
            }

    float z[2][2][4] = {};   // [hh][qt][r]
    size_t krow = ((size_t)(b * Ln + ck * 512 + lq)) * Dd + lg * 8;
    for (int step = 0; step < 32; ++step) {
        size_t kstep = krow + (size_t)step * 16 * Dd;
#pragma unroll
        for (int hh = 0; hh < 2; ++hh) {
            const short* kR = (const short*)kh_g + kstep + (h0 + hh) * 64;
            const short* lR = (const short*)kl_g + kstep + (h0 + hh) * 64;
            short8 bh0 = *(const short8*)&kR[0],  bh1 = *(const short8*)&kR[32];
            short8 bl0 = *(const short8*)&lR[0],  bl1 = *(const short8*)&lR[32];
#pragma unroll
            for (int qt = 0; qt < 2; ++qt) {
                f32x4 acc = {};
                MFMA6(acc, AH[qt][hh][0], AH[qt][hh][1], AL[qt][hh][0], AL[qt][hh][1],
                      bh0, bh1, bl0, bl1);
#pragma unroll
                for (int r = 0; r < 4; ++r) z[hh][qt][r] += __expf(acc[r]);
            }
        }
    }
#pragma unroll
    for (int hh = 0; hh < 2; ++hh)
#pragma unroll
        for (int qt = 0; qt < 2; ++qt)
#pragma unroll
            for (int r = 0; r < 4; ++r) {
                float v = z[hh][qt][r];
                v += __shfl_xor(v, 1); v += __shfl_xor(v, 2);
                v += __shfl_xor(v, 4); v += __shfl_xor(v, 8);
                z[hh][qt][r] = v;
            }
    if (lq == 0) {
#pragma unroll
        for (int hh = 0; hh < 2; ++hh)
#pragma unroll
            for (int qt = 0; qt < 2; ++qt)
#pragma unroll
                for (int r = 0; r < 4; ++r) {
                    int q = q0 + qt * 16 + lg * 4 + r;
                    zpart[((size_t)(ck * 2 + b) * NPn + q) * 8 + h0 + hh] = z[hh][qt][r];
                }
    }
}

// izs[b][q][h] = 1 / (8 * sum_ck zpart)
__global__ __launch_bounds__(256) void zreduce(
    const float* __restrict__ zpart, float* __restrict__ izs)
{
    int g = blockIdx.x * 256 + threadIdx.x;   // 32768
    int b = g >> 14, q = (g >> 3) & 2047, h = g & 7;
    float s = 0.f;
#pragma unroll
    for (int c = 0; c < 8; ++c)
        s += zpart[((size_t)(c * 2 + b) * NPn + q) * 8 + h];
    izs[g] = 1.0f / (8.0f * s);
}

// ---------------------------------------------------------------------------
// Pass 2: 32-query tile, 1024-key chunk per block (partials over 4 chunks).
// Grid 512 flat: combo = id&7 -> (b, ck 0..3) [1 combo per XCD], q16 = id>>3.
// 8 waves; wave wv scores keys wv*16 of each 128-tile (all 8 heads, qt=2),
// then PV on d-cols [wv*64, wv*64+64). h-outer over 256-key groups to cut
// LDS re-reads. Writes UNNORMALIZED Opart + rpart.
// ---------------------------------------------------------------------------
__global__ __launch_bounds__(512, 4) void attn_pass2(
    const ushort* __restrict__ qh_g, const ushort* __restrict__ ql_g,
    const ushort* __restrict__ kh_g, const ushort* __restrict__ kl_g,
    const ushort* __restrict__ vh_g, const ushort* __restrict__ vl_g,
    const float* __restrict__ izs,
    float* __restrict__ Opart, float* __restrict__ rpart)
{
    __shared__ __align__(16) short8 qhs[2048];   // 32 q x 64 c8, swizzled
    __shared__ __align__(16) short8 qls[2048];
    __shared__ __align__(16) ushort Ps[32 * 128];
    __shared__ float izss[256];
    __shared__ float rss[8][32];

    int orig = blockIdx.x;
    int combo = orig & 7, b = combo & 1, ck = combo >> 1;
    int q0 = (orig >> 3) * 32;
    int t = threadIdx.x, wv = t >> 6, ln = t & 63;
    int lq = ln & 15, lg = ln >> 4;
    const short8* qh8 = (const short8*)qh_g;
    const short8* ql8 = (const short8*)ql_g;
    const short8* Ps8 = (const short8*)Ps;

#pragma unroll
    for (int it = 0; it < 4; ++it) {
        int idx = it * 512 + t; int r = idx >> 6;
        int slot = idx ^ (r & 7);
        qhs[slot] = qh8[(size_t)(q0 + r) * 64 + (idx & 63)];
        qls[slot] = ql8[(size_t)(q0 + r) * 64 + (idx & 63)];
    }
    if (t < 256) izss[t] = izs[((size_t)b * NPn + q0 + (t >> 3)) * 8 + (t & 7)];
    __syncthreads();

    f32x4 oacc[2][4] = {};            // [qt][n]
    float racc[2][4] = {};            // [qt][r]

    for (int g = 0; g < 4; ++g) {     // 256-key groups
        int t0 = ck * 1024 + g * 256;
        float p[2][2][4] = {};        // [kt][qt][r]
        size_t krow = ((size_t)(b * Ln + t0 + wv * 16 + lq)) * Dd + lg * 8;
#pragma unroll
        for (int h = 0; h < 8; ++h) {
            short8 ah0[2], ah1[2], al0[2], al1[2];
#pragma unroll
            for (int qt = 0; qt < 2; ++qt) {
                int row = qt * 16 + lq;
                int base = row * 64 + h * 8;
                int sw = row & 7;
                ah0[qt] = qhs[(base + lg) ^ sw];
                ah1[qt] = qhs[(base + 4 + lg) ^ sw];
                al0[qt] = qls[(base + lg) ^ sw];
                al1[qt] = qls[(base + 4 + lg) ^ sw];
            }
#pragma unroll
            for (int kt = 0; kt < 2; ++kt) {
                const short* kR = (const short*)kh_g + krow + (size_t)kt * 128 * Dd + h * 64;
                const short* lR = (const short*)kl_g + krow + (size_t)kt * 128 * Dd + h * 64;
                short8 bh0 = *(const short8*)&kR[0],  bh1 = *(const short8*)&kR[32];
                short8 bl0 = *(const short8*)&lR[0],  bl1 = *(const short8*)&lR[32];
#pragma unroll
                for (int qt = 0; qt < 2; ++qt) {
                    f32x4 acc = {};
                    MFMA6(acc, ah0[qt], ah1[qt], al0[qt], al1[qt], bh0, bh1, bl0, bl1);
#pragma unroll
                    for (int r = 0; r < 4; ++r)
                        p[kt][qt][r] += __expf(acc[r]) * izss[(qt * 16 + lg * 4 + r) * 8 + h];
                }
            }
        }
#pragma unroll
        for (int kt = 0; kt < 2; ++kt) {
#pragma unroll
            for (int qt = 0; qt < 2; ++qt)
#pragma unroll
                for (int r = 0; r < 4; ++r) {
                    int q = qt * 16 + lg * 4 + r;
                    float wgt = __expf(INV_T * __logf(p[kt][qt][r]));
                    ushort uw = bf16_rne(wgt);
                    racc[qt][r] += bf16_tof(uw);
                    int e = q * 128 + wv * 16 + lq;
                    Ps[e ^ ((q & 7) << 3)] = uw;
                }
            __syncthreads();
            short8 pa[2][4];
#pragma unroll
            for (int qt = 0; qt < 2; ++qt)
#pragma unroll
                for (int ks = 0; ks < 4; ++ks) {
                    int row = qt * 16 + lq;
                    pa[qt][ks] = Ps8[(row * 16 + ks * 4 + lg) ^ (row & 7)];
                }
#pragma unroll
            for (int n = 0; n < 4; ++n) {
                size_t vrow = ((size_t)(b * Dd + wv * 64 + n * 16 + lq)) * Ln
                              + t0 + kt * 128 + lg * 8;
                const short* vR = (const short*)vh_g + vrow;
                const short* wR = (const short*)vl_g + vrow;
#pragma unroll
                for (int ks = 0; ks < 4; ++ks) {
                    short8 bh = *(const short8*)&vR[ks * 32];
                    short8 bl = *(const short8*)&wR[ks * 32];
#pragma unroll
                    for (int qt = 0; qt < 2; ++qt) {
                        oacc[qt][n] = __builtin_amdgcn_mfma_f32_16x16x32_bf16(pa[qt][ks], bh, oacc[qt][n], 0, 0, 0);
                        oacc[qt][n] = __builtin_amdgcn_mfma_f32_16x16x32_bf16(pa[qt][ks], bl, oacc[qt][n], 0, 0, 0);
                    }
                }
            }
            __syncthreads();
        }
    }

#pragma unroll
    for (int qt = 0; qt < 2; ++qt)
#pragma unroll
        for (int r = 0; r < 4; ++r) {
            float v = racc[qt][r];
            v += __shfl_xor(v, 1); v += __shfl_xor(v, 2);
            v += __shfl_xor(v, 4); v += __shfl_xor(v, 8);
            racc[qt][r] = v;
        }
    if (lq == 0) {
#pragma unroll
        for (int qt = 0; qt < 2; ++qt)
#pragma unroll
            for (int r = 0; r < 4; ++r) rss[wv][qt * 16 + lg * 4 + r] = racc[qt][r];
    }
    __syncthreads();
    if (t < 32) {
        float s = 0.f;
#pragma unroll
        for (int w2 = 0; w2 < 8; ++w2) s += rss[w2][t];
        rpart[(size_t)(ck * 2 + b) * NPn + q0 + t] = s;
    }
#pragma unroll
    for (int qt = 0; qt < 2; ++qt)
#pragma unroll
        for (int n = 0; n < 4; ++n)
#pragma unroll
            for (int r = 0; r < 4; ++r) {
                int q = q0 + qt * 16 + lg * 4 + r;
                int d = wv * 64 + n * 16 + lq;
                Opart[((size_t)(ck * 2 + b) * NPn + q) * Dd + d] = oacc[qt][n][r];
            }
}

// out = (sum_ck Opart) / (sum_ck rpart)
__global__ __launch_bounds__(256) void finalize(
    const float* __restrict__ Opart, const float* __restrict__ rpart,
    float* __restrict__ out)
{
    int idx = blockIdx.x * 256 + threadIdx.x;   // f32x4 units: 524288 total
    int d4 = idx & 127, q = (idx >> 7) & 2047, b = idx >> 18;
    float rs = 0.f;
#pragma unroll
    for (int c = 0; c < 4; ++c) rs += rpart[(size_t)(c * 2 + b) * NPn + q];
    float ox = 0.f, oy = 0.f, oz = 0.f, ow = 0.f;
#pragma unroll
    for (int c = 0; c < 4; ++c) {
        float4 v = ((const float4*)Opart)[((size_t)(c * 2 + b) * NPn + q) * 128 + d4];
        ox += v.x; oy += v.y; oz += v.z; ow += v.w;
    }
    float inv = 1.0f / rs;
    ((float4*)out)[idx] = make_float4(ox * inv, oy * inv, oz * inv, ow * inv);
}

// ---------------------------------------------------------------------------
extern "C" void kernel_launch(void* const* d_in, const int* in_sizes, int n_in,
                              void* d_out, int out_size, void* d_ws, size_t ws_size,
                              hipStream_t stream)
{
    (void)in_sizes; (void)n_in; (void)out_size; (void)ws_size;
    const float* x       = (const float*)d_in[0];
    const float* queries = (const float*)d_in[1];
    const float* wq      = (const float*)d_in[2];
    const float* wk      = (const float*)d_in[3];
    const float* bq      = (const float*)d_in[4];
    const float* bk      = (const float*)d_in[5];
    const float* gq      = (const float*)d_in[6];
    const float* betq    = (const float*)d_in[7];
    const float* gx      = (const float*)d_in[8];
    const float* betx    = (const float*)d_in[9];

    const size_t XN = (size_t)Bn * Ln * Dd;     // 4,194,304
    const size_t QN = (size_t)NPn * Dd;         // 1,048,576
    const size_t WN = (size_t)Dd * Dd;          //   262,144

    ushort* u = (ushort*)d_ws;
    ushort* xh  = u;             ushort* xl  = xh + XN;
    ushort* qnh = xl + XN;       ushort* qnl = qnh + QN;
    ushort* wqh = qnl + QN;      ushort* wql = wqh + WN;
    ushort* wkh = wql + WN;      ushort* wkl = wkh + WN;
    ushort* kh  = wkl + WN;      ushort* kl  = kh + XN;
    ushort* qh  = kl + XN;       ushort* ql  = qh + QN;
    ushort* vh  = ql + QN;       ushort* vl  = vh + XN;
    float* f = (float*)(vl + XN);
    float* zpart = f;                            // 16*2048*8 = 262,144
    float* izs   = zpart + 262144;               // 32,768
    float* rpart = izs + 32768;                  // 8*2048 = 16,384
    float* Opart = rpart + 16384;                // 8*2048*512 = 8,388,608
    // total ws ~= 95.6 MB

    ln_split<<<Bn * Ln + NPn, 64, 0, stream>>>(x, queries, gx, betx, gq, betq,
                                               xh, xl, qnh, qnl);
    wsplit<<<512, 256, 0, stream>>>(wq, wk, wqh, wql, wkh, wkl);
    proj_mfma<<<dim3((Bn * Ln) / 64, 2), 256, 0, stream>>>(xh, xl, wkh, wkl, bk, kh, kl, 1.0f);
    proj_mfma<<<dim3(NPn / 64, 2), 256, 0, stream>>>(qnh, qnl, wqh, wql, bq, qh, ql, 0.125f);
    transpose_u16<<<dim3(Ln / 64, Dd / 64, Bn), 256, 0, stream>>>(xh, xl, vh, vl);
    attn_pass1<<<1024, 256, 0, stream>>>(qh, ql, kh, kl, zpart);
    zreduce<<<128, 256, 0, stream>>>(zpart, izs);
    attn_pass2<<<512, 512, 0, stream>>>(qh, ql, kh, kl, vh, vl, izs, Opart, rpart);
    finalize<<<2048, 256, 0, stream>>>(Opart, rpart, (float*)d_out);
}